// Round 4
// baseline (111.999 us; speedup 1.0000x reference)
//
#include <hip/hip_runtime.h>

// weights[M,81] = z[M,256] @ W^T + b (masked at idx 0,1,9); out[M] = sum_idx w*x0^p*x1^k
// fp16 MFMA GEMM, permuted B columns (MFMA col cc of tile n -> real col 6*cc+n),
// mask folded into zeroed B columns, fused low-VALU epilogue, 2 M-tiles/block.

typedef _Float16 half8 __attribute__((ext_vector_type(8)));
typedef __fp16 fp16x2 __attribute__((ext_vector_type(2)));
typedef float f32x4 __attribute__((ext_vector_type(4)));

constexpr int NW = 81;     // (P+1)^2
constexpr int KD = 256;    // n
constexpr int BROWS = 256; // rows per block: 2 tiles x 128 (4 waves x 32)
constexpr int NT = 6;      // N tiles of 16 (real col = 6*cc + n, <81)
constexpr int KT = 8;      // K steps of 32

__global__ __launch_bounds__(256, 3) void poly_mfma(
    const float* __restrict__ x,     // [npos][2]
    const float* __restrict__ z,     // [npos][256]
    const float* __restrict__ W,     // [81][256]
    const float* __restrict__ bias,  // [81]
    float* __restrict__ out,         // [npos]
    float* __restrict__ wout,        // [npos][81]
    int npos)
{
    __shared__ _Float16 Bl[NT * KT * 64 * 8];   // 48 KiB

    const int tid = threadIdx.x;

    // ---- stage W -> fp16 fragments (permuted cols; masked cols zeroed) ----
    for (int i = tid; i < NT * KT * 64; i += 256) {
        const int n   = i >> 9;          // / (KT*64)
        const int rem = i & 511;
        const int kk  = rem >> 6;
        const int l   = rem & 63;
        const int cc  = l & 15;
        const int col = 6 * cc + n;      // permuted real column
        const int k0  = kk * 32 + ((l >> 4) << 3);
        union { half8 v; fp16x2 p[4]; } u;
        const bool dead = (col > 80) || col == 0 || col == 1 || col == 9;
        if (!dead) {
            const float* wp = W + col * KD + k0;
            const float4 a = *reinterpret_cast<const float4*>(wp);
            const float4 b = *reinterpret_cast<const float4*>(wp + 4);
            u.p[0] = __builtin_amdgcn_cvt_pkrtz(a.x, a.y);
            u.p[1] = __builtin_amdgcn_cvt_pkrtz(a.z, a.w);
            u.p[2] = __builtin_amdgcn_cvt_pkrtz(b.x, b.y);
            u.p[3] = __builtin_amdgcn_cvt_pkrtz(b.z, b.w);
        } else {
            u.p[0] = __builtin_amdgcn_cvt_pkrtz(0.f, 0.f);
            u.p[1] = u.p[0]; u.p[2] = u.p[0]; u.p[3] = u.p[0];
        }
        *reinterpret_cast<half8*>(&Bl[(size_t)i * 8]) = u.v;
    }
    __syncthreads();

    const int lane = tid & 63;
    const int wv   = tid >> 6;
    const int c    = lane & 15;      // MFMA column cc / A-row within tile
    const int g    = lane >> 4;

    const int base = blockIdx.x * BROWS + wv * 32;   // rows of tile0 for this wave

    // per-lane constants for the power ladder: first idx = 6c -> p0, k0
    const int p0 = (6 * c) / 9;
    const int k0 = (6 * c) % 9;      // in {0,3,6} for c<=13

    // bias preload (masked, clamped)
    float bv[6];
#pragma unroll
    for (int n = 0; n < 6; ++n) {
        const int idx  = 6 * c + n;
        const int cidx = idx > 80 ? 80 : idx;
        const float bb = bias[cidx];
        const bool dead = (idx > 80) || idx == 0 || idx == 1 || idx == 9;
        bv[n] = dead ? 0.f : bb;
    }

    // A-row pointers for both tiles
    const float* zAr[2], * zBr[2];
#pragma unroll
    for (int tt = 0; tt < 2; ++tt) {
        int rA = base + tt * 128 + c;       if (rA >= npos) rA = npos - 1;
        int rB = base + tt * 128 + 16 + c;  if (rB >= npos) rB = npos - 1;
        zAr[tt] = z + (size_t)rA * KD + g * 8;
        zBr[tt] = z + (size_t)rB * KD + g * 8;
    }

    // prologue: kk=0 of tile 0
    float4 ca0 = *reinterpret_cast<const float4*>(zAr[0]);
    float4 ca1 = *reinterpret_cast<const float4*>(zAr[0] + 4);
    float4 cb0 = *reinterpret_cast<const float4*>(zBr[0]);
    float4 cb1 = *reinterpret_cast<const float4*>(zBr[0] + 4);

#pragma unroll
    for (int tt = 0; tt < 2; ++tt) {
        // x pre-load for this tile's 8 epilogue positions (latency hidden by K-loop)
        float2 xp[8];
#pragma unroll
        for (int i = 0; i < 8; ++i) {
            const int t = i >> 2, rg = i & 3;
            int pp = base + tt * 128 + t * 16 + g * 4 + rg;
            if (pp >= npos) pp = npos - 1;
            xp[i] = *reinterpret_cast<const float2*>(x + 2 * (size_t)pp);
        }

        f32x4 acc0[NT], acc1[NT];
#pragma unroll
        for (int n = 0; n < NT; ++n) { acc0[n] = (f32x4)(0.f); acc1[n] = (f32x4)(0.f); }

#pragma unroll
        for (int kk = 0; kk < KT; ++kk) {
            // prefetch next K-step (or next tile's kk=0)
            float4 na0, na1, nb0, nb1;
            if (kk < KT - 1) {
                na0 = *reinterpret_cast<const float4*>(zAr[tt] + (kk + 1) * 32);
                na1 = *reinterpret_cast<const float4*>(zAr[tt] + (kk + 1) * 32 + 4);
                nb0 = *reinterpret_cast<const float4*>(zBr[tt] + (kk + 1) * 32);
                nb1 = *reinterpret_cast<const float4*>(zBr[tt] + (kk + 1) * 32 + 4);
            } else if (tt == 0) {
                na0 = *reinterpret_cast<const float4*>(zAr[1]);
                na1 = *reinterpret_cast<const float4*>(zAr[1] + 4);
                nb0 = *reinterpret_cast<const float4*>(zBr[1]);
                nb1 = *reinterpret_cast<const float4*>(zBr[1] + 4);
            } else {
                na0 = ca0; na1 = ca1; nb0 = cb0; nb1 = cb1;
            }

            union { half8 v; fp16x2 p[4]; } uA, uB;
            uA.p[0] = __builtin_amdgcn_cvt_pkrtz(ca0.x, ca0.y);
            uA.p[1] = __builtin_amdgcn_cvt_pkrtz(ca0.z, ca0.w);
            uA.p[2] = __builtin_amdgcn_cvt_pkrtz(ca1.x, ca1.y);
            uA.p[3] = __builtin_amdgcn_cvt_pkrtz(ca1.z, ca1.w);
            uB.p[0] = __builtin_amdgcn_cvt_pkrtz(cb0.x, cb0.y);
            uB.p[1] = __builtin_amdgcn_cvt_pkrtz(cb0.z, cb0.w);
            uB.p[2] = __builtin_amdgcn_cvt_pkrtz(cb1.x, cb1.y);
            uB.p[3] = __builtin_amdgcn_cvt_pkrtz(cb1.z, cb1.w);
            const half8 A0 = uA.v;
            const half8 A1 = uB.v;

#pragma unroll
            for (int n = 0; n < NT; ++n) {
                const half8 Bf = *reinterpret_cast<const half8*>(
                    &Bl[(size_t)((n * KT + kk) * 64 + lane) * 8]);
                acc0[n] = __builtin_amdgcn_mfma_f32_16x16x32_f16(A0, Bf, acc0[n], 0, 0, 0);
                acc1[n] = __builtin_amdgcn_mfma_f32_16x16x32_f16(A1, Bf, acc1[n], 0, 0, 0);
            }
            ca0 = na0; ca1 = na1; cb0 = nb0; cb1 = nb1;
        }

        // ---- epilogue for this tile ----
#pragma unroll
        for (int t = 0; t < 2; ++t) {
#pragma unroll
            for (int rg = 0; rg < 4; ++rg) {
                const int pos = base + tt * 128 + t * 16 + g * 4 + rg;
                const bool vp = pos < npos;
                const float x0 = xp[t * 4 + rg].x;
                const float x1 = xp[t * 4 + rg].y;
                const float x0_2 = x0 * x0, x0_4 = x0_2 * x0_2, x0_8 = x0_4 * x0_4;
                const float x1_2 = x1 * x1, x1_4 = x1_2 * x1_2;
                // q0sel = x0^p0 (p0 in 0..8), q1sel = x1^k0 (k0 in {0,3,6})
                const float q0sel = ((p0 & 1) ? x0 : 1.f) * ((p0 & 2) ? x0_2 : 1.f)
                                  * ((p0 & 4) ? x0_4 : 1.f) * ((p0 & 8) ? x0_8 : 1.f);
                const float q1sel = ((k0 & 1) ? x1 : 1.f) * ((k0 & 2) ? x1_2 : 1.f)
                                  * ((k0 & 4) ? x1_4 : 1.f);
                const float qa = q0sel * q1sel;     // x0^p0 * x1^k0  (idx = 6c)
                const float qb = q0sel * x0;        // x0^(p0+1)      (wrap target)

                float q = qa;
                float ws[6];
                float wsum = 0.f;
#pragma unroll
                for (int n = 0; n < 6; ++n) {
                    const float a = (t == 0) ? acc0[n][rg] : acc1[n][rg];
                    const float w = a + bv[n];      // masked cols: a=0, bv=0 -> w=0
                    ws[n] = w;
                    wsum = fmaf(w, q, wsum);
                    // next q: wrap only happens at n==2 for k0==6 lanes
                    if (n == 2) q = (k0 == 6) ? qb : q * x1;
                    else        q = q * x1;
                }

                if (vp) {
                    float* bp = wout + (size_t)pos * NW + 6 * c;
                    if (c < 13) {
                        float4 v4; v4.x = ws[0]; v4.y = ws[1]; v4.z = ws[2]; v4.w = ws[3];
                        float2 v2; v2.x = ws[4]; v2.y = ws[5];
                        *reinterpret_cast<float4*>(bp) = v4;
                        *reinterpret_cast<float2*>(bp + 4) = v2;
                    } else if (c == 13) {            // idx 78,79,80
                        float2 v2; v2.x = ws[0]; v2.y = ws[1];
                        *reinterpret_cast<float2*>(bp) = v2;
                        bp[2] = ws[2];
                    }
                }

                // reduce over the 16 column-lanes sharing this row
                wsum += __shfl_xor(wsum, 1, 64);
                wsum += __shfl_xor(wsum, 2, 64);
                wsum += __shfl_xor(wsum, 4, 64);
                wsum += __shfl_xor(wsum, 8, 64);
                if (c == 0 && vp) out[pos] = wsum;
            }
        }
    }
}

extern "C" void kernel_launch(void* const* d_in, const int* in_sizes, int n_in,
                              void* d_out, int out_size, void* d_ws, size_t ws_size,
                              hipStream_t stream) {
    const float* x = (const float*)d_in[0];
    const float* z = (const float*)d_in[1];
    const float* W = (const float*)d_in[2];
    const float* b = (const float*)d_in[3];

    const int npos = in_sizes[0] / 2;   // B*L
    float* out  = (float*)d_out;        // [npos]
    float* wout = out + npos;           // [npos][81]

    const int grid = (npos + BROWS - 1) / BROWS;
    hipLaunchKernelGGL(poly_mfma, dim3(grid), dim3(256), 0, stream,
                       x, z, W, b, out, wout, npos);
}

// Round 5
// 84.123 us; speedup vs baseline: 1.3314x; 1.3314x over previous
//
#include <hip/hip_runtime.h>

// weights[M,81] = z[M,256] @ W^T + b (mask at idx 0,1,9); out[M] = sum w*x0^p*x1^k
// fp16 MFMA. z staged via LDS with CONTIGUOUS row-major global loads (DRAM
// locality), XOR-swizzled A rows in LDS. B (W) pre-expanded fragments,
// permuted col = 6*cc + n, masked cols zeroed. 2 blocks/CU antiphase.

typedef _Float16 half8 __attribute__((ext_vector_type(8)));
typedef __fp16 fp16x2 __attribute__((ext_vector_type(2)));
typedef float f32x4 __attribute__((ext_vector_type(4)));

constexpr int NW = 81;
constexpr int KD = 256;
constexpr int NT = 6;     // col tiles of 16 (real col = 6*cc + n)
constexpr int KT = 8;     // K steps of 32
constexpr int RC = 64;    // rows per chunk (LDS A buffer)
constexpr int NCH = 8;    // chunks per block -> 512 rows per block

__global__ __launch_bounds__(256, 2) void poly_mfma(
    const float* __restrict__ x,     // [npos][2]
    const float* __restrict__ z,     // [npos][256]
    const float* __restrict__ W,     // [81][256]
    const float* __restrict__ bias,  // [81]
    float* __restrict__ out,         // [npos]
    float* __restrict__ wout,        // [npos][81]
    int npos)
{
    __shared__ _Float16 Bl[NT * KT * 64 * 8];   // 48 KiB B fragments
    __shared__ _Float16 Al[RC * KD];            // 32 KiB A chunk (swizzled rows)

    const int tid  = threadIdx.x;
    const int lane = tid & 63;
    const int wv   = tid >> 6;       // wave 0..3
    const int c    = lane & 15;      // MFMA col cc / A row within half-tile
    const int g    = lane >> 4;      // k-group 0..3

    // ---- stage W -> fp16 B fragments (permuted cols; masked cols zeroed) ----
    for (int i = tid; i < NT * KT * 64; i += 256) {
        const int n   = i >> 9;
        const int rem = i & 511;
        const int kk  = rem >> 6;
        const int l   = rem & 63;
        const int cc  = l & 15;
        const int col = 6 * cc + n;
        const int k0i = kk * 32 + ((l >> 4) << 3);
        union { half8 v; fp16x2 p[4]; } u;
        const bool dead = (col > 80) || col == 0 || col == 1 || col == 9;
        if (!dead) {
            const float* wp = W + col * KD + k0i;
            const float4 a = *reinterpret_cast<const float4*>(wp);
            const float4 b = *reinterpret_cast<const float4*>(wp + 4);
            u.p[0] = __builtin_amdgcn_cvt_pkrtz(a.x, a.y);
            u.p[1] = __builtin_amdgcn_cvt_pkrtz(a.z, a.w);
            u.p[2] = __builtin_amdgcn_cvt_pkrtz(b.x, b.y);
            u.p[3] = __builtin_amdgcn_cvt_pkrtz(b.z, b.w);
        } else {
            u.p[0] = __builtin_amdgcn_cvt_pkrtz(0.f, 0.f);
            u.p[1] = u.p[0]; u.p[2] = u.p[0]; u.p[3] = u.p[0];
        }
        *reinterpret_cast<half8*>(&Bl[(size_t)i * 8]) = u.v;
    }

    // per-lane epilogue constants: first idx = 6c -> p0, k0 (k0 in {0,3,6})
    const int p0 = (6 * c) / 9;
    const int k0 = (6 * c) % 9;
    float bv[6];
#pragma unroll
    for (int n = 0; n < 6; ++n) {
        const int idx  = 6 * c + n;
        const int cidx = idx > 80 ? 80 : idx;
        const float bb = bias[cidx];
        const bool dead = (idx > 80) || idx == 0 || idx == 1 || idx == 9;
        bv[n] = dead ? 0.f : bb;
    }

    const int blockbase = blockIdx.x * (RC * NCH);

    // z staging addressing: thread covers 8 rows (2 per q), 32 B each half-row
    //   row_local = wv*16 + q*2 + (lane>>5); float offset = (lane&31)*8
    const int rl_off = wv * 16 + (lane >> 5);
    const int fo     = (lane & 31) * 8;

    float4 f[16];
    // prologue: contiguous loads of chunk 0
#pragma unroll
    for (int q = 0; q < 8; ++q) {
        int r = blockbase + rl_off + q * 2;
        r = r < npos ? r : npos - 1;
        const float* rp = z + (size_t)r * KD + fo;
        f[q * 2 + 0] = *reinterpret_cast<const float4*>(rp);
        f[q * 2 + 1] = *reinterpret_cast<const float4*>(rp + 4);
    }

    for (int ch = 0; ch < NCH; ++ch) {
        const int rowbase = blockbase + ch * RC;

        __syncthreads();   // prior compute finished reading Al

        // stage chunk ch: cvt fp32->fp16, swizzled ds_write_b128
        {
            const int bytec = (lane & 31) * 16;   // fp16 byte offset within row
#pragma unroll
            for (int q = 0; q < 8; ++q) {
                const int rl = rl_off + q * 2;
                union { half8 v; fp16x2 p[4]; } u;
                u.p[0] = __builtin_amdgcn_cvt_pkrtz(f[q*2].x,   f[q*2].y);
                u.p[1] = __builtin_amdgcn_cvt_pkrtz(f[q*2].z,   f[q*2].w);
                u.p[2] = __builtin_amdgcn_cvt_pkrtz(f[q*2+1].x, f[q*2+1].y);
                u.p[3] = __builtin_amdgcn_cvt_pkrtz(f[q*2+1].z, f[q*2+1].w);
                const int byte = (rl * 512 + bytec) ^ ((rl & 7) << 4);
                *reinterpret_cast<half8*>(reinterpret_cast<char*>(Al) + byte) = u.v;
            }
        }

        __syncthreads();   // Al ready

        // issue next chunk's contiguous global loads (overlap with compute)
        if (ch + 1 < NCH) {
#pragma unroll
            for (int q = 0; q < 8; ++q) {
                int r = rowbase + RC + rl_off + q * 2;
                r = r < npos ? r : npos - 1;
                const float* rp = z + (size_t)r * KD + fo;
                f[q * 2 + 0] = *reinterpret_cast<const float4*>(rp);
                f[q * 2 + 1] = *reinterpret_cast<const float4*>(rp + 4);
            }
        }

        // x preload for this wave's 16 epilogue rows
        float2 xp[4];
#pragma unroll
        for (int rg = 0; rg < 4; ++rg) {
            int pp = rowbase + wv * 16 + g * 4 + rg;
            pp = pp < npos ? pp : npos - 1;
            xp[rg] = *reinterpret_cast<const float2*>(x + 2 * (size_t)pp);
        }

        // compute: per kk, 1 A-frag read + 6 B-frag reads + 6 MFMA
        f32x4 acc[NT];
#pragma unroll
        for (int n = 0; n < NT; ++n) acc[n] = (f32x4)(0.f);

#pragma unroll
        for (int kk = 0; kk < KT; ++kk) {
            const int rl = wv * 16 + c;
            const int abyte = (rl * 512 + kk * 64 + g * 16) ^ ((c & 7) << 4);
            const half8 Af = *reinterpret_cast<const half8*>(
                reinterpret_cast<const char*>(Al) + abyte);
#pragma unroll
            for (int n = 0; n < NT; ++n) {
                const half8 Bf = *reinterpret_cast<const half8*>(
                    &Bl[(size_t)((n * KT + kk) * 64 + lane) * 8]);
                acc[n] = __builtin_amdgcn_mfma_f32_16x16x32_f16(Af, Bf, acc[n], 0, 0, 0);
            }
        }

        // ---- epilogue: bias, store wout, fused out-reduction ----
#pragma unroll
        for (int rg = 0; rg < 4; ++rg) {
            const int pos = rowbase + wv * 16 + g * 4 + rg;
            const bool vp = pos < npos;
            const float x0 = xp[rg].x, x1 = xp[rg].y;
            const float x0_2 = x0 * x0, x0_4 = x0_2 * x0_2, x0_8 = x0_4 * x0_4;
            const float x1_2 = x1 * x1, x1_4 = x1_2 * x1_2;
            const float q0sel = ((p0 & 1) ? x0 : 1.f) * ((p0 & 2) ? x0_2 : 1.f)
                              * ((p0 & 4) ? x0_4 : 1.f) * ((p0 & 8) ? x0_8 : 1.f);
            const float q1sel = ((k0 & 1) ? x1 : 1.f) * ((k0 & 2) ? x1_2 : 1.f)
                              * ((k0 & 4) ? x1_4 : 1.f);
            const float qa = q0sel * q1sel;   // x0^p0 * x1^k0 (idx = 6c)
            const float qb = q0sel * x0;      // x0^(p0+1) (wrap target)

            float q = qa;
            float ws[6];
            float wsum = 0.f;
#pragma unroll
            for (int n = 0; n < 6; ++n) {
                const float w = acc[n][rg] + bv[n];  // dead cols: 0 + 0
                ws[n] = w;
                wsum = fmaf(w, q, wsum);
                if (n == 2) q = (k0 == 6) ? qb : q * x1;
                else        q = q * x1;
            }

            if (vp) {
                float* bp = wout + (size_t)pos * NW + 6 * c;
                if (c < 13) {
                    float4 v4; v4.x = ws[0]; v4.y = ws[1]; v4.z = ws[2]; v4.w = ws[3];
                    float2 v2; v2.x = ws[4]; v2.y = ws[5];
                    *reinterpret_cast<float4*>(bp) = v4;
                    *reinterpret_cast<float2*>(bp + 4) = v2;
                } else if (c == 13) {          // idx 78,79,80
                    float2 v2; v2.x = ws[0]; v2.y = ws[1];
                    *reinterpret_cast<float2*>(bp) = v2;
                    bp[2] = ws[2];
                }
            }

            wsum += __shfl_xor(wsum, 1, 64);
            wsum += __shfl_xor(wsum, 2, 64);
            wsum += __shfl_xor(wsum, 4, 64);
            wsum += __shfl_xor(wsum, 8, 64);
            if (c == 0 && vp) out[pos] = wsum;
        }
    }
}

extern "C" void kernel_launch(void* const* d_in, const int* in_sizes, int n_in,
                              void* d_out, int out_size, void* d_ws, size_t ws_size,
                              hipStream_t stream) {
    const float* x = (const float*)d_in[0];
    const float* z = (const float*)d_in[1];
    const float* W = (const float*)d_in[2];
    const float* b = (const float*)d_in[3];

    const int npos = in_sizes[0] / 2;   // B*L = 262144
    float* out  = (float*)d_out;        // [npos]
    float* wout = out + npos;           // [npos][81]

    const int rows_per_block = RC * NCH;   // 512
    const int grid = (npos + rows_per_block - 1) / rows_per_block;
    hipLaunchKernelGGL(poly_mfma, dim3(grid), dim3(256), 0, stream,
                       x, z, W, b, out, wout, npos);
}